// Round 14
// baseline (401.005 us; speedup 1.0000x reference)
//
#include <hip/hip_runtime.h>

// Ensemble of 8 LSTMs (H=64, input dim 1) over T=1024, B=128, then (B,T)@Wl^T+bl.
//
// v14: K-split P=4 — dedup'd MFMA + dedup'd trans at 2 waves/SIMD.
//  - 256 blocks (8 L x 32 groups of 4 batches) x 512 threads (8 waves).
//    Wave (pw=w&3, kh=w>>2): unit-tile pw, K-half kh. 4 INDEPENDENT MFMAs/wave
//    (4 gates x 1 khalf; bias via kh0 C-init). A rows = h[batch m&3] (dup4).
//    D: col=unit-in-tile, reg=batch -> lane (col,kg) selects reg kg = its cell
//    (batch kg, unit 16pw+col): 64 unique cells per cell-wave, zero trans dup.
//  - kh1 writes its selected partial (f32x4) to pbuf[pw][kg][col] (linear per
//    lane, conflict-free b128); barrier; kh0 adds own+partner, does the cell
//    update, writes h (bf16, swizzled hbuf) + h63 ring; barrier.
//  - Per-SIMD issue/step ~290 cyc (vs v13's ~703): MFMA 8x17.5 + VALU ~150.
//  - h ping-pong; projection after loop (8 waves); reduce kernel sums L.

#define LENA 8
#define NB 128
#define NT 1024
#define NH 64

typedef __attribute__((ext_vector_type(4))) float f32x4;
typedef __attribute__((ext_vector_type(8))) short bf16x8;

__device__ __forceinline__ short f2bf(float f) {
    unsigned u = __float_as_uint(f);
    unsigned r = (u + 0x7FFFu + ((u >> 16) & 1u)) >> 16;
    return (short)r;
}

__global__ __launch_bounds__(512, 2) void lstm_v14_kernel(
    const float* __restrict__ x, const float* __restrict__ hn,
    const float* __restrict__ Wih, const float* __restrict__ Whh,
    const float* __restrict__ bih, const float* __restrict__ bhh,
    const float* __restrict__ Wl, float* __restrict__ ws)
{
    __shared__ float x4[NT][4];                          // 16 KB
    __shared__ float ring[NT][4];                        // 16 KB: h63 history
    __shared__ __align__(16) short hbuf[2][32][8];       // 1 KB: ping-pong h, swizzled
    __shared__ __align__(16) float pbuf[4][4][16][4];    // 4 KB: [pw][kg][col][gate]
    __shared__ float pws[8][8];

    const int tid = threadIdx.x;
    const int w   = tid >> 6;        // wave 0..7
    const int pw  = w & 3;           // unit-tile
    const int kh  = w >> 2;          // k-half (0: cell wave, 1: partner)
    const int l   = tid & 63;
    const int col = l & 15;          // unit-in-tile (A/B row, D col)
    const int kg  = l >> 4;          // lane's batch
    const int li  = blockIdx.x >> 5; // LSTM 0..7
    const int bg  = blockIdx.x & 31; // 4-batch group
    const int b0  = bg * 4;

    // ---- stage x ----
    for (int i = tid; i < 4 * NT; i += 512) {
        int bx = i >> 10, t = i & (NT - 1);
        x4[t][bx] = x[(size_t)(b0 + bx) * NT + t];
    }
    // ---- stage h0: slot(b,s) = b*8 + (s ^ 2b) ----
    if (tid < 256) {
        int b = tid >> 6, u = tid & 63;
        float v = hn[((size_t)li * NB + b0 + b) * NH + u];
        int slot = b * 8 + ((u >> 3) ^ (2 * b));
        hbuf[0][slot][u & 7] = f2bf(v);
    }

    const float RLN2 = 1.44269504f;   // 1/ln2
    // ---- B-frags for OWN khalf: row = 64g+16pw+col, k = kh*32 + kg*8 + e ----
    bf16x8 bfr[4];
    #pragma unroll
    for (int g = 0; g < 4; ++g) {
        const float sc = (g == 2) ? 2.0f * RLN2 : RLN2;
        const float* q = Whh + ((size_t)li * 256 + 64 * g + 16 * pw + col) * 64 + kh * 32 + kg * 8;
        bf16x8 f;
        #pragma unroll
        for (int e = 0; e < 8; ++e) f[e] = f2bf(sc * q[e]);
        bfr[g] = f;
    }
    // ---- per-lane cell constants: cell (b=kg, u=16pw+col) ----
    const int u_c = 16 * pw + col;
    float wih4[4];
    f32x4 cinit[4];
    #pragma unroll
    for (int g = 0; g < 4; ++g) {
        const float sc = (g == 2) ? 2.0f * RLN2 : RLN2;
        int rowc = li * 256 + 64 * g + u_c;
        wih4[g] = sc * Wih[rowc];
        float bv = (kh == 0) ? sc * (bih[rowc] + bhh[rowc]) : 0.0f;  // bias only in kh0
        cinit[g][0] = bv; cinit[g][1] = bv; cinit[g][2] = bv; cinit[g][3] = bv;
    }

    // ---- A-read slot for own khalf: A row m = h[batch m&3], lane reads b_r=col&3 ----
    const int b_r = col & 3;
    const int sA = b_r * 8 + (((kh << 2) + kg) ^ (2 * b_r));
    // ---- h-write slot for this lane's cell ----
    const int wslot = kg * 8 + ((u_c >> 3) ^ (2 * kg));
    const int wpos  = u_c & 7;
    const bool isring = (u_c == 63);

    float cst = 0.0f;   // carries 2/ln2 scale internally

    __syncthreads();

    #pragma unroll 2
    for (int t = 0; t < NT; ++t) {
        const int p = t & 1;
        bf16x8 a = *(const bf16x8*)&hbuf[p][sA][0];

        f32x4 acc[4];
        __builtin_amdgcn_s_setprio(1);
        #pragma unroll
        for (int g = 0; g < 4; ++g)
            acc[g] = __builtin_amdgcn_mfma_f32_16x16x32_bf16(a, bfr[g], cinit[g], 0, 0, 0);
        __builtin_amdgcn_s_setprio(0);
        __builtin_amdgcn_sched_barrier(0);

        // select reg kg (this lane's batch) per gate
        f32x4 se;
        #pragma unroll
        for (int g = 0; g < 4; ++g) {
            float va = (kg & 1) ? acc[g][1] : acc[g][0];
            float vb = (kg & 1) ? acc[g][3] : acc[g][2];
            se[g] = (kg & 2) ? vb : va;
        }

        if (kh) {   // partner wave: ship partial (linear per lane -> conflict-free)
            *(f32x4*)&pbuf[pw][kg][col][0] = se;
        }
        __syncthreads();   // barA: partials visible

        if (!kh) {  // cell wave
            f32x4 pp = *(const f32x4*)&pbuf[pw][kg][col][0];
            const float xv = x4[t][kg];
            float gi = fmaf(xv, wih4[0], se[0] + pp[0]);
            float gf = fmaf(xv, wih4[1], se[1] + pp[1]);
            float gg = fmaf(xv, wih4[2], se[2] + pp[2]);
            float go = fmaf(xv, wih4[3], se[3] + pp[3]);

            float iv = __builtin_amdgcn_rcpf(1.0f + __builtin_amdgcn_exp2f(-gi));
            float fv = __builtin_amdgcn_rcpf(1.0f + __builtin_amdgcn_exp2f(-gf));
            // gt' = (2/ln2)*tanh(g)
            float gt = fmaf(-5.77078016f, __builtin_amdgcn_rcpf(1.0f + __builtin_amdgcn_exp2f(gg)), 2.88539008f);
            float ov = __builtin_amdgcn_rcpf(1.0f + __builtin_amdgcn_exp2f(-go));
            cst = fmaf(fv, cst, iv * gt);   // cst = (2/ln2) * c_true
            float ct = fmaf(-2.0f, __builtin_amdgcn_rcpf(1.0f + __builtin_amdgcn_exp2f(cst)), 1.0f);
            float hh = ov * ct;

            unsigned pk;
            asm("v_cvt_pk_bf16_f32 %0, %1, %2" : "=v"(pk) : "v"(hh), "v"(hh));
            hbuf[p ^ 1][wslot][wpos] = (short)(pk & 0xffffu);
            if (isring) ring[t][kg] = hh;
        }
        __syncthreads();   // barB: h(t+1) visible
    }

    // ---- projection: wave w -> batch b=w&3, half hf=w>>2 ----
    {
        const int b = w & 3, hf = w >> 2;
        const int a = l & 7, ch = l >> 3;
        const int tb = hf * 512 + ch * 64;
        const float* wlp = Wl + (size_t)a * NT + tb;
        float pacc = 0.0f;
        #pragma unroll 4
        for (int i = 0; i < 64; ++i)
            pacc = fmaf(ring[tb + i][b], wlp[i], pacc);
        pacc += __shfl_xor(pacc, 8);
        pacc += __shfl_xor(pacc, 16);
        pacc += __shfl_xor(pacc, 32);
        if (l < 8) pws[w][a] = pacc;
    }
    __syncthreads();
    if (tid < 32) {
        int b = tid >> 3, a = tid & 7;
        ws[(size_t)blockIdx.x * 32 + b * 8 + a] = pws[b][a] + pws[b + 4][a];
    }
}

__global__ __launch_bounds__(256) void reduce_kernel(
    const float* __restrict__ ws, const float* __restrict__ bl, float* __restrict__ out)
{
    int tid = blockIdx.x * 256 + threadIdx.x;    // 0..1023
    if (tid >= NB * LENA) return;
    int b = tid >> 3, a = tid & 7;
    int bg = b >> 2, bx = b & 3;
    float s = bl[a];
    #pragma unroll
    for (int li = 0; li < LENA; ++li)
        s += ws[((size_t)(li * 32 + bg)) * 32 + bx * 8 + a];
    out[tid] = s;
}

extern "C" void kernel_launch(void* const* d_in, const int* in_sizes, int n_in,
                              void* d_out, int out_size, void* d_ws, size_t ws_size,
                              hipStream_t stream) {
    const float* x   = (const float*)d_in[0];
    const float* hn  = (const float*)d_in[1];
    const float* Wih = (const float*)d_in[2];
    const float* Whh = (const float*)d_in[3];
    const float* bih = (const float*)d_in[4];
    const float* bhh = (const float*)d_in[5];
    const float* Wl  = (const float*)d_in[6];
    const float* bl  = (const float*)d_in[7];
    float* out = (float*)d_out;
    float* ws  = (float*)d_ws;   // 256*32*4 = 32 KB

    lstm_v14_kernel<<<dim3(256), dim3(512), 0, stream>>>(x, hn, Wih, Whh, bih, bhh, Wl, ws);
    reduce_kernel<<<dim3(4), dim3(256), 0, stream>>>(ws, bl, out);
}

// Round 15
// 262.791 us; speedup vs baseline: 1.5259x; 1.5259x over previous
//
#include <hip/hip_runtime.h>

// Ensemble of 8 LSTMs (H=64, input dim 1) over T=1024, B=128, then (B,T)@Wl^T+bl.
//
// v15 = v13 (512 blocks x 4 waves, 2 blocks/CU, 2 waves/SIMD, sched-pinned)
// + exact issue cuts:
//  - reg0 trick: A rows hold batch (m>>2)&1, so reg 0 of lane (col,kg) IS its
//    cell's gate partial -> all 4 cndmask selects deleted.
//  - merged-rcp activations (exact algebra):
//      iv*gt' = 2.885(Eg-1) * rcp((1+Ei)(1+Eg)),  Ei=exp2(-gi), Eg=exp2(gg)
//      h      = (Ec-1) * rcp((1+Eo)(1+Ec)),       Eo=exp2(-go), Ec=exp2(cst)
//    10 -> 8 trans ops per cell.
//  - everything else v13: Whh bf16 pre-scaled (1/ln2; g gate 2/ln2), bias via
//    MFMA C-init, chained kh MFMAs, setprio+sched_barrier, xv prefetch,
//    swizzled hbuf ping-pong, 1 barrier/step, h63 ring -> post-loop projection.

#define LENA 8
#define NB 128
#define NT 1024
#define NH 64

typedef __attribute__((ext_vector_type(4))) float f32x4;
typedef __attribute__((ext_vector_type(8))) short bf16x8;

__device__ __forceinline__ short f2bf(float f) {
    unsigned u = __float_as_uint(f);
    unsigned r = (u + 0x7FFFu + ((u >> 16) & 1u)) >> 16;
    return (short)r;
}

__global__ __launch_bounds__(256, 2) void lstm_v15_kernel(
    const float* __restrict__ x, const float* __restrict__ hn,
    const float* __restrict__ Wih, const float* __restrict__ Whh,
    const float* __restrict__ bih, const float* __restrict__ bhh,
    const float* __restrict__ Wl, float* __restrict__ ws)
{
    __shared__ float x2[NT][2];                      // 8 KB
    __shared__ float ring[NT][2];                    // 8 KB: h63 history
    __shared__ __align__(16) short hbuf[2][16][8];   // 512 B: ping-pong h, swizzled slots
    __shared__ float pws[2][2][8];                   // projection partials

    const int tid = threadIdx.x;
    const int w   = tid >> 6;        // wave 0..3: owns unit-tile w
    const int l   = tid & 63;
    const int col = l & 15;          // unit-in-tile (A/B row, D col)
    const int kg  = l >> 4;          // k-group
    const int bb  = kg & 1;          // lane's batch (kg and kg+2 duplicate)
    const int li  = blockIdx.x >> 6; // LSTM 0..7
    const int bg  = blockIdx.x & 63; // batch pair
    const int b0  = bg * 2;

    // ---- stage x ----
    for (int i = tid; i < 2 * NT; i += 256) {
        int bx = i >> 10, t = i & (NT - 1);
        x2[t][bx] = x[(size_t)(b0 + bx) * NT + t];
    }
    // ---- stage h0 into swizzled hbuf[0]: slot(b,s) = b*8 + (s ^ 2b) ----
    if (tid < 128) {
        int b = tid >> 6, u = tid & 63;
        float v = hn[((size_t)li * NB + b0 + b) * NH + u];
        int slot = b * 8 + ((u >> 3) ^ (2 * b));
        hbuf[0][slot][u & 7] = f2bf(v);
    }

    const float RLN2 = 1.44269504f;   // 1/ln2
    // ---- B-frags: bf[gate][khalf], row = 64g+16w+col, k = kh*32 + kg*8 + e ----
    bf16x8 bf[4][2];
    #pragma unroll
    for (int g = 0; g < 4; ++g) {
        const float sc = (g == 2) ? 2.0f * RLN2 : RLN2;
        const float* rp = Whh + ((size_t)li * 256 + 64 * g + 16 * w + col) * 64 + kg * 8;
        #pragma unroll
        for (int kh = 0; kh < 2; ++kh) {
            const float* q = rp + kh * 32;
            bf16x8 f;
            #pragma unroll
            for (int e = 0; e < 8; ++e) f[e] = f2bf(sc * q[e]);
            bf[g][kh] = f;
        }
    }
    // ---- per-lane cell constants: cell (b=bb, u=16w+col) ----
    const int u_c = 16 * w + col;
    float wih4[4];
    f32x4 cinit[4];
    #pragma unroll
    for (int g = 0; g < 4; ++g) {
        const float sc = (g == 2) ? 2.0f * RLN2 : RLN2;
        int rowc = li * 256 + 64 * g + u_c;
        wih4[g] = sc * Wih[rowc];
        float bv = sc * (bih[rowc] + bhh[rowc]);
        cinit[g][0] = bv; cinit[g][1] = bv; cinit[g][2] = bv; cinit[g][3] = bv;
    }

    // ---- A-read: A row m = h[batch (m>>2)&1]; lane's A-row is col ----
    const int b_r = (col >> 2) & 1;                     // reg0 = lane's own batch
    const int s0 = b_r * 8 + (kg ^ (2 * b_r));          // khalf0
    const int s1 = b_r * 8 + ((4 + kg) ^ (2 * b_r));    // khalf1
    // ---- h-write slot (batch-indexed: kg and kg+2 write same addr/value) ----
    const int wslot = bb * 8 + ((u_c >> 3) ^ (2 * bb));
    const int wpos  = u_c & 7;
    const bool isring = (u_c == 63);

    float cst = 0.0f;   // carries 2/ln2 scale internally

    __syncthreads();

    #pragma unroll 2
    for (int t = 0; t < NT; ++t) {
        const int p = t & 1;
        bf16x8 a0 = *(const bf16x8*)&hbuf[p][s0][0];
        bf16x8 a1 = *(const bf16x8*)&hbuf[p][s1][0];
        const float xv = x2[t][bb];    // prefetched; lgkm hides under MFMA issue

        f32x4 acc[4];
        __builtin_amdgcn_s_setprio(1);
        #pragma unroll
        for (int g = 0; g < 4; ++g) {
            f32x4 a = __builtin_amdgcn_mfma_f32_16x16x32_bf16(a0, bf[g][0], cinit[g], 0, 0, 0);
            acc[g] = __builtin_amdgcn_mfma_f32_16x16x32_bf16(a1, bf[g][1], a, 0, 0, 0);
        }
        __builtin_amdgcn_s_setprio(0);
        __builtin_amdgcn_sched_barrier(0);   // keep MFMA cluster intact; accs live

        // reg0 = this lane's batch for every gate (no selects)
        float gi = fmaf(xv, wih4[0], acc[0][0]);
        float gf = fmaf(xv, wih4[1], acc[1][0]);
        float gg = fmaf(xv, wih4[2], acc[2][0]);
        float go = fmaf(xv, wih4[3], acc[3][0]);

        // merged-rcp activations (exact):
        float Ei = __builtin_amdgcn_exp2f(-gi);
        float Ef = __builtin_amdgcn_exp2f(-gf);
        float Eg = __builtin_amdgcn_exp2f(gg);
        float Eo = __builtin_amdgcn_exp2f(-go);
        float fv = __builtin_amdgcn_rcpf(1.0f + Ef);
        // iv*gt' = 2.88539(Eg-1) * rcp((1+Ei)(1+Eg))
        float ivgt = fmaf(2.88539008f, Eg, -2.88539008f)
                   * __builtin_amdgcn_rcpf((1.0f + Ei) * (1.0f + Eg));
        cst = fmaf(fv, cst, ivgt);     // cst = (2/ln2) * c_true
        float Ec = __builtin_amdgcn_exp2f(cst);
        // h = (Ec-1) * rcp((1+Eo)(1+Ec))
        float hh = (Ec - 1.0f) * __builtin_amdgcn_rcpf((1.0f + Eo) * (1.0f + Ec));

        unsigned pk;
        asm("v_cvt_pk_bf16_f32 %0, %1, %2" : "=v"(pk) : "v"(hh), "v"(hh));
        hbuf[p ^ 1][wslot][wpos] = (short)(pk & 0xffffu);
        if (isring) ring[t][bb] = hh;
        __syncthreads();
    }

    // ---- projection: wave w -> batch b=w>>1, half p2=w&1 ----
    {
        const int b = w >> 1, p2 = w & 1;
        const int a = l & 7, ch = l >> 3;
        const int tb = p2 * 512 + ch * 64;
        const float* wlp = Wl + (size_t)a * NT + tb;
        float pacc = 0.0f;
        #pragma unroll 4
        for (int i = 0; i < 64; ++i)
            pacc = fmaf(ring[tb + i][b], wlp[i], pacc);
        pacc += __shfl_xor(pacc, 8);
        pacc += __shfl_xor(pacc, 16);
        pacc += __shfl_xor(pacc, 32);
        if (l < 8) pws[b][p2][a] = pacc;
    }
    __syncthreads();
    if (tid < 16) {
        int b = tid >> 3, a = tid & 7;
        ws[((size_t)blockIdx.x * 2 + b) * 8 + a] = pws[b][0][a] + pws[b][1][a];
    }
}

__global__ __launch_bounds__(256) void reduce_kernel(
    const float* __restrict__ ws, const float* __restrict__ bl, float* __restrict__ out)
{
    int tid = blockIdx.x * 256 + threadIdx.x;    // 0..1023
    if (tid >= NB * LENA) return;
    int b = tid >> 3, a = tid & 7;
    int bg = b >> 1, bx = b & 1;
    float s = bl[a];
    #pragma unroll
    for (int li = 0; li < LENA; ++li)
        s += ws[(((size_t)li * 64 + bg) * 2 + bx) * 8 + a];
    out[tid] = s;
}

extern "C" void kernel_launch(void* const* d_in, const int* in_sizes, int n_in,
                              void* d_out, int out_size, void* d_ws, size_t ws_size,
                              hipStream_t stream) {
    const float* x   = (const float*)d_in[0];
    const float* hn  = (const float*)d_in[1];
    const float* Wih = (const float*)d_in[2];
    const float* Whh = (const float*)d_in[3];
    const float* bih = (const float*)d_in[4];
    const float* bhh = (const float*)d_in[5];
    const float* Wl  = (const float*)d_in[6];
    const float* bl  = (const float*)d_in[7];
    float* out = (float*)d_out;
    float* ws  = (float*)d_ws;   // 512*2*8*4 = 32 KB

    lstm_v15_kernel<<<dim3(512), dim3(256), 0, stream>>>(x, hn, Wih, Whh, bih, bhh, Wl, ws);
    reduce_kernel<<<dim3(4), dim3(256), 0, stream>>>(ws, bl, out);
}

// Round 16
// 249.878 us; speedup vs baseline: 1.6048x; 1.0517x over previous
//
#include <hip/hip_runtime.h>

// Ensemble of 8 LSTMs (H=64, input dim 1) over T=1024, B=128, then (B,T)@Wl^T+bl.
//
// v16 = v13 + reg0 trick ONLY (v15 confounded it with merged-rcp, which
// lengthened the serial chain to h and flipped the kernel latency-bound).
//  - A rows hold batch (m>>2)&1 -> D regs 0..3 of lane-group kg are all batch
//    kg&1, so reg 0 IS the lane's own cell gate: all 4 cndmask selects deleted,
//    zero change to the dependent path.
//  - activations: v13 form (separate exp2/rcp per gate, folded tanh scale:
//    cst carries 2/ln2; gt' = fmaf(-4/ln2, rcp, 2/ln2)).
//  - geometry: 512 blocks (8 L x 64 batch-pairs) x 4 waves, 2 blocks/CU,
//    2 waves/SIMD; chained kh MFMAs, bias via C-init, setprio+sched_barrier,
//    xv prefetch, swizzled hbuf ping-pong, 1 barrier/step, h63 ring ->
//    post-loop projection; reduce kernel sums over L.

#define LENA 8
#define NB 128
#define NT 1024
#define NH 64

typedef __attribute__((ext_vector_type(4))) float f32x4;
typedef __attribute__((ext_vector_type(8))) short bf16x8;

__device__ __forceinline__ short f2bf(float f) {
    unsigned u = __float_as_uint(f);
    unsigned r = (u + 0x7FFFu + ((u >> 16) & 1u)) >> 16;
    return (short)r;
}

__global__ __launch_bounds__(256, 2) void lstm_v16_kernel(
    const float* __restrict__ x, const float* __restrict__ hn,
    const float* __restrict__ Wih, const float* __restrict__ Whh,
    const float* __restrict__ bih, const float* __restrict__ bhh,
    const float* __restrict__ Wl, float* __restrict__ ws)
{
    __shared__ float x2[NT][2];                      // 8 KB
    __shared__ float ring[NT][2];                    // 8 KB: h63 history
    __shared__ __align__(16) short hbuf[2][16][8];   // 512 B: ping-pong h, swizzled slots
    __shared__ float pws[2][2][8];                   // projection partials

    const int tid = threadIdx.x;
    const int w   = tid >> 6;        // wave 0..3: owns unit-tile w
    const int l   = tid & 63;
    const int col = l & 15;          // unit-in-tile (A/B row, D col)
    const int kg  = l >> 4;          // k-group
    const int bb  = kg & 1;          // lane's batch (kg and kg+2 duplicate)
    const int li  = blockIdx.x >> 6; // LSTM 0..7
    const int bg  = blockIdx.x & 63; // batch pair
    const int b0  = bg * 2;

    // ---- stage x ----
    for (int i = tid; i < 2 * NT; i += 256) {
        int bx = i >> 10, t = i & (NT - 1);
        x2[t][bx] = x[(size_t)(b0 + bx) * NT + t];
    }
    // ---- stage h0 into swizzled hbuf[0]: slot(b,s) = b*8 + (s ^ 2b) ----
    if (tid < 128) {
        int b = tid >> 6, u = tid & 63;
        float v = hn[((size_t)li * NB + b0 + b) * NH + u];
        int slot = b * 8 + ((u >> 3) ^ (2 * b));
        hbuf[0][slot][u & 7] = f2bf(v);
    }

    const float RLN2 = 1.44269504f;   // 1/ln2
    // ---- B-frags: bf[gate][khalf], row = 64g+16w+col, k = kh*32 + kg*8 + e ----
    bf16x8 bf[4][2];
    #pragma unroll
    for (int g = 0; g < 4; ++g) {
        const float sc = (g == 2) ? 2.0f * RLN2 : RLN2;
        const float* rp = Whh + ((size_t)li * 256 + 64 * g + 16 * w + col) * 64 + kg * 8;
        #pragma unroll
        for (int kh = 0; kh < 2; ++kh) {
            const float* q = rp + kh * 32;
            bf16x8 f;
            #pragma unroll
            for (int e = 0; e < 8; ++e) f[e] = f2bf(sc * q[e]);
            bf[g][kh] = f;
        }
    }
    // ---- per-lane cell constants: cell (b=bb, u=16w+col) ----
    const int u_c = 16 * w + col;
    float wih4[4];
    f32x4 cinit[4];
    #pragma unroll
    for (int g = 0; g < 4; ++g) {
        const float sc = (g == 2) ? 2.0f * RLN2 : RLN2;
        int rowc = li * 256 + 64 * g + u_c;
        wih4[g] = sc * Wih[rowc];
        float bv = sc * (bih[rowc] + bhh[rowc]);
        cinit[g][0] = bv; cinit[g][1] = bv; cinit[g][2] = bv; cinit[g][3] = bv;
    }

    // ---- A-read: A row m = h[batch (m>>2)&1]; lane's A-row is col ----
    const int b_r = (col >> 2) & 1;                     // reg0 = lane's own batch
    const int s0 = b_r * 8 + (kg ^ (2 * b_r));          // khalf0
    const int s1 = b_r * 8 + ((4 + kg) ^ (2 * b_r));    // khalf1
    // ---- h-write slot (batch-indexed: kg and kg+2 write same addr/value) ----
    const int wslot = bb * 8 + ((u_c >> 3) ^ (2 * bb));
    const int wpos  = u_c & 7;
    const bool isring = (u_c == 63);

    float cst = 0.0f;   // carries 2/ln2 scale internally

    __syncthreads();

    #pragma unroll 2
    for (int t = 0; t < NT; ++t) {
        const int p = t & 1;
        bf16x8 a0 = *(const bf16x8*)&hbuf[p][s0][0];
        bf16x8 a1 = *(const bf16x8*)&hbuf[p][s1][0];
        const float xv = x2[t][bb];    // prefetched; lgkm hides under MFMA issue

        f32x4 acc[4];
        __builtin_amdgcn_s_setprio(1);
        #pragma unroll
        for (int g = 0; g < 4; ++g) {
            f32x4 a = __builtin_amdgcn_mfma_f32_16x16x32_bf16(a0, bf[g][0], cinit[g], 0, 0, 0);
            acc[g] = __builtin_amdgcn_mfma_f32_16x16x32_bf16(a1, bf[g][1], a, 0, 0, 0);
        }
        __builtin_amdgcn_s_setprio(0);
        __builtin_amdgcn_sched_barrier(0);   // keep MFMA cluster intact; accs live

        // reg0 = this lane's batch for every gate (no selects)
        float gi = fmaf(xv, wih4[0], acc[0][0]);
        float gf = fmaf(xv, wih4[1], acc[1][0]);
        float gg = fmaf(xv, wih4[2], acc[2][0]);
        float go = fmaf(xv, wih4[3], acc[3][0]);

        float iv = __builtin_amdgcn_rcpf(1.0f + __builtin_amdgcn_exp2f(-gi));
        float fv = __builtin_amdgcn_rcpf(1.0f + __builtin_amdgcn_exp2f(-gf));
        // gt' = (2/ln2)*tanh(g) = fmaf(-4/ln2, rcp(1+e^{2g}), 2/ln2)
        float gt = fmaf(-5.77078016f, __builtin_amdgcn_rcpf(1.0f + __builtin_amdgcn_exp2f(gg)), 2.88539008f);
        float ov = __builtin_amdgcn_rcpf(1.0f + __builtin_amdgcn_exp2f(-go));
        cst = fmaf(fv, cst, iv * gt);   // cst = (2/ln2) * c_true
        float ct = fmaf(-2.0f, __builtin_amdgcn_rcpf(1.0f + __builtin_amdgcn_exp2f(cst)), 1.0f);
        float hh = ov * ct;

        unsigned pk;
        asm("v_cvt_pk_bf16_f32 %0, %1, %2" : "=v"(pk) : "v"(hh), "v"(hh));
        hbuf[p ^ 1][wslot][wpos] = (short)(pk & 0xffffu);
        if (isring) ring[t][bb] = hh;
        __syncthreads();
    }

    // ---- projection: wave w -> batch b=w>>1, half p2=w&1 ----
    {
        const int b = w >> 1, p2 = w & 1;
        const int a = l & 7, ch = l >> 3;
        const int tb = p2 * 512 + ch * 64;
        const float* wlp = Wl + (size_t)a * NT + tb;
        float pacc = 0.0f;
        #pragma unroll 4
        for (int i = 0; i < 64; ++i)
            pacc = fmaf(ring[tb + i][b], wlp[i], pacc);
        pacc += __shfl_xor(pacc, 8);
        pacc += __shfl_xor(pacc, 16);
        pacc += __shfl_xor(pacc, 32);
        if (l < 8) pws[b][p2][a] = pacc;
    }
    __syncthreads();
    if (tid < 16) {
        int b = tid >> 3, a = tid & 7;
        ws[((size_t)blockIdx.x * 2 + b) * 8 + a] = pws[b][0][a] + pws[b][1][a];
    }
}

__global__ __launch_bounds__(256) void reduce_kernel(
    const float* __restrict__ ws, const float* __restrict__ bl, float* __restrict__ out)
{
    int tid = blockIdx.x * 256 + threadIdx.x;    // 0..1023
    if (tid >= NB * LENA) return;
    int b = tid >> 3, a = tid & 7;
    int bg = b >> 1, bx = b & 1;
    float s = bl[a];
    #pragma unroll
    for (int li = 0; li < LENA; ++li)
        s += ws[(((size_t)li * 64 + bg) * 2 + bx) * 8 + a];
    out[tid] = s;
}

extern "C" void kernel_launch(void* const* d_in, const int* in_sizes, int n_in,
                              void* d_out, int out_size, void* d_ws, size_t ws_size,
                              hipStream_t stream) {
    const float* x   = (const float*)d_in[0];
    const float* hn  = (const float*)d_in[1];
    const float* Wih = (const float*)d_in[2];
    const float* Whh = (const float*)d_in[3];
    const float* bih = (const float*)d_in[4];
    const float* bhh = (const float*)d_in[5];
    const float* Wl  = (const float*)d_in[6];
    const float* bl  = (const float*)d_in[7];
    float* out = (float*)d_out;
    float* ws  = (float*)d_ws;   // 512*2*8*4 = 32 KB

    lstm_v16_kernel<<<dim3(512), dim3(256), 0, stream>>>(x, hn, Wih, Whh, bih, bhh, Wl, ws);
    reduce_kernel<<<dim3(4), dim3(256), 0, stream>>>(ws, bl, out);
}

// Round 18
// 242.078 us; speedup vs baseline: 1.6565x; 1.0322x over previous
//
#include <hip/hip_runtime.h>

// Ensemble of 8 LSTMs (H=64, input dim 1) over T=1024, B=128, then (B,T)@Wl^T+bl.
//
// v18 = v17 (trans-split across dup2 lane pair) with the permlane exchange done
// via __builtin_amdgcn_permlane32_swap (raw inline asm in v17 hit the
// VALU->permlane read hazard: compiler inserts wait-states only for intrinsics).
//  - role = kg>=2. Gates i,f,o weights/bias/wih NEGATED so Ea=exp2(ga) uniform.
//    role0 computes i,f (iv,fv); role1 computes g,o (gt',ov). Partner values
//    cross the lane-32 boundary via permlane32_swap: result[1] in lanes<32 is
//    the partner's value. Per-lane trans 10 -> 6.
//  - Only kg<2 lanes hold real hh: real h/ring writes; kg>=2 -> LDS scratch.
//  - Rest = v16: 512 blocks x 4 waves, 2 blocks/CU, 2 waves/SIMD; A rows =
//    h[batch (m>>2)&1] (reg0 trick); chained kh MFMAs, bias via C-init;
//    setprio + sched_barrier; swizzled hbuf ping-pong; 1 barrier/step;
//    h63 ring -> post-loop projection; reduce kernel sums over L.

#define LENA 8
#define NB 128
#define NT 1024
#define NH 64

typedef __attribute__((ext_vector_type(4))) float f32x4;
typedef __attribute__((ext_vector_type(8))) short bf16x8;

__device__ __forceinline__ short f2bf(float f) {
    unsigned u = __float_as_uint(f);
    unsigned r = (u + 0x7FFFu + ((u >> 16) & 1u)) >> 16;
    return (short)r;
}

__global__ __launch_bounds__(256, 2) void lstm_v18_kernel(
    const float* __restrict__ x, const float* __restrict__ hn,
    const float* __restrict__ Wih, const float* __restrict__ Whh,
    const float* __restrict__ bih, const float* __restrict__ bhh,
    const float* __restrict__ Wl, float* __restrict__ ws)
{
    __shared__ float x2[NT][2];                      // 8 KB
    __shared__ float ring[NT][2];                    // 8 KB: h63 history
    __shared__ __align__(16) short hbuf[2][16][8];   // 512 B: ping-pong h, swizzled slots
    __shared__ short scratch[256];                   // 512 B: per-lane dummy-write slots
    __shared__ float pws[2][2][8];                   // projection partials

    const int tid = threadIdx.x;
    const int w   = tid >> 6;        // wave 0..3: owns unit-tile w
    const int l   = tid & 63;
    const int col = l & 15;          // unit-in-tile (A/B row, D col)
    const int kg  = l >> 4;          // k-group
    const int bb  = kg & 1;          // lane's batch (kg and kg+2 duplicate)
    const bool role = (kg >= 2);     // 0: gates i,f   1: gates g,o
    const int li  = blockIdx.x >> 6; // LSTM 0..7
    const int bg  = blockIdx.x & 63; // batch pair
    const int b0  = bg * 2;

    // ---- stage x ----
    for (int i = tid; i < 2 * NT; i += 256) {
        int bx = i >> 10, t = i & (NT - 1);
        x2[t][bx] = x[(size_t)(b0 + bx) * NT + t];
    }
    // ---- stage h0 into swizzled hbuf[0]: slot(b,s) = b*8 + (s ^ 2b) ----
    if (tid < 128) {
        int b = tid >> 6, u = tid & 63;
        float v = hn[((size_t)li * NB + b0 + b) * NH + u];
        int slot = b * 8 + ((u >> 3) ^ (2 * b));
        hbuf[0][slot][u & 7] = f2bf(v);
    }

    const float RLN2 = 1.44269504f;   // 1/ln2
    // gate scales: i,f,o NEGATED; g gets +2/ln2
    // ---- B-frags: bf[gate][khalf], row = 64g+16w+col, k = kh*32 + kg*8 + e ----
    bf16x8 bf[4][2];
    #pragma unroll
    for (int g = 0; g < 4; ++g) {
        const float sc = (g == 2) ? 2.0f * RLN2 : -RLN2;
        const float* rp = Whh + ((size_t)li * 256 + 64 * g + 16 * w + col) * 64 + kg * 8;
        #pragma unroll
        for (int kh = 0; kh < 2; ++kh) {
            const float* q = rp + kh * 32;
            bf16x8 f;
            #pragma unroll
            for (int e = 0; e < 8; ++e) f[e] = f2bf(sc * q[e]);
            bf[g][kh] = f;
        }
    }
    // ---- per-lane cell constants: cell (b=bb, u=16w+col) ----
    const int u_c = 16 * w + col;
    float wih4[4];
    f32x4 cinit[4];
    #pragma unroll
    for (int g = 0; g < 4; ++g) {
        const float sc = (g == 2) ? 2.0f * RLN2 : -RLN2;
        int rowc = li * 256 + 64 * g + u_c;
        wih4[g] = sc * Wih[rowc];
        float bv = sc * (bih[rowc] + bhh[rowc]);
        cinit[g][0] = bv; cinit[g][1] = bv; cinit[g][2] = bv; cinit[g][3] = bv;
    }
    // role-selected x-weights (loop-invariant)
    const float wih_a = role ? wih4[2] : wih4[0];
    const float wih_b = role ? wih4[3] : wih4[1];

    // ---- A-read: A row m = h[batch (m>>2)&1]; reg0 = lane's own batch ----
    const int b_r = (col >> 2) & 1;
    const int s0 = b_r * 8 + (kg ^ (2 * b_r));          // khalf0
    const int s1 = b_r * 8 + ((4 + kg) ^ (2 * b_r));    // khalf1
    // ---- h-write: real slot for kg<2, per-lane scratch otherwise ----
    const int wslot = bb * 8 + ((u_c >> 3) ^ (2 * bb));
    const int wpos  = u_c & 7;
    short* const wr0 = (kg < 2) ? &hbuf[1][wslot][wpos] : &scratch[tid];  // for p=0
    short* const wr1 = (kg < 2) ? &hbuf[0][wslot][wpos] : &scratch[tid];  // for p=1
    const bool isring = (u_c == 63) && (kg < 2);   // lanes 15,31 of wave 3

    float cst = 0.0f;   // carries 2/ln2 scale internally (garbage on role1 lanes)

    __syncthreads();

    #pragma unroll 2
    for (int t = 0; t < NT; ++t) {
        const int p = t & 1;
        bf16x8 a0 = *(const bf16x8*)&hbuf[p][s0][0];
        bf16x8 a1 = *(const bf16x8*)&hbuf[p][s1][0];
        const float xv = x2[t][bb];

        f32x4 acc[4];
        __builtin_amdgcn_s_setprio(1);
        #pragma unroll
        for (int g = 0; g < 4; ++g) {
            f32x4 a = __builtin_amdgcn_mfma_f32_16x16x32_bf16(a0, bf[g][0], cinit[g], 0, 0, 0);
            acc[g] = __builtin_amdgcn_mfma_f32_16x16x32_bf16(a1, bf[g][1], a, 0, 0, 0);
        }
        __builtin_amdgcn_s_setprio(0);
        __builtin_amdgcn_sched_barrier(0);   // keep MFMA cluster intact; accs live

        // role-selected gate pair (reg0 = own batch)
        float ga = fmaf(xv, wih_a, role ? acc[2][0] : acc[0][0]);
        float gb = fmaf(xv, wih_b, role ? acc[3][0] : acc[1][0]);

        float Ea = __builtin_amdgcn_exp2f(ga);
        float Eb = __builtin_amdgcn_exp2f(gb);
        float ra = __builtin_amdgcn_rcpf(1.0f + Ea);   // role0: iv   role1: rcp(1+Eg)
        float rb = __builtin_amdgcn_rcpf(1.0f + Eb);   // role0: fv   role1: ov

        // gt' = (2/ln2)*tanh(g) on role1 lanes (garbage on role0)
        float gtX = fmaf(-5.77078016f, ra, 2.88539008f);

        // exchange via intrinsic (handles VALU->permlane hazard):
        // result[1] in lanes<32 = partner lane's (lane+32) value.
        unsigned gu = __float_as_uint(gtX);
        auto rg = __builtin_amdgcn_permlane32_swap(gu, gu, false, false);
        float g2 = __uint_as_float(rg[1]);
        unsigned ou = __float_as_uint(rb);
        auto ro = __builtin_amdgcn_permlane32_swap(ou, ou, false, false);
        float o2 = __uint_as_float(ro[1]);
        // lanes<32: g2 = partner gt', o2 = partner ov

        cst = fmaf(rb, cst, ra * g2);   // role0: fmaf(fv, cst, iv*gt')
        float Ec = __builtin_amdgcn_exp2f(cst);
        float ct = fmaf(-2.0f, __builtin_amdgcn_rcpf(1.0f + Ec), 1.0f);
        float hh = o2 * ct;             // role0 lanes: real h; role1: garbage

        unsigned pk;
        asm("v_cvt_pk_bf16_f32 %0, %1, %2" : "=v"(pk) : "v"(hh), "v"(hh));
        *(p ? wr1 : wr0) = (short)pk;
        if (isring) ring[t][bb] = hh;
        __syncthreads();
    }

    // ---- projection: wave w -> batch b=w>>1, half p2=w&1 ----
    {
        const int b = w >> 1, p2 = w & 1;
        const int a = l & 7, ch = l >> 3;
        const int tb = p2 * 512 + ch * 64;
        const float* wlp = Wl + (size_t)a * NT + tb;
        float pacc = 0.0f;
        #pragma unroll 4
        for (int i = 0; i < 64; ++i)
            pacc = fmaf(ring[tb + i][b], wlp[i], pacc);
        pacc += __shfl_xor(pacc, 8);
        pacc += __shfl_xor(pacc, 16);
        pacc += __shfl_xor(pacc, 32);
        if (l < 8) pws[b][p2][a] = pacc;
    }
    __syncthreads();
    if (tid < 16) {
        int b = tid >> 3, a = tid & 7;
        ws[((size_t)blockIdx.x * 2 + b) * 8 + a] = pws[b][0][a] + pws[b][1][a];
    }
}

__global__ __launch_bounds__(256) void reduce_kernel(
    const float* __restrict__ ws, const float* __restrict__ bl, float* __restrict__ out)
{
    int tid = blockIdx.x * 256 + threadIdx.x;    // 0..1023
    if (tid >= NB * LENA) return;
    int b = tid >> 3, a = tid & 7;
    int bg = b >> 1, bx = b & 1;
    float s = bl[a];
    #pragma unroll
    for (int li = 0; li < LENA; ++li)
        s += ws[(((size_t)li * 64 + bg) * 2 + bx) * 8 + a];
    out[tid] = s;
}

extern "C" void kernel_launch(void* const* d_in, const int* in_sizes, int n_in,
                              void* d_out, int out_size, void* d_ws, size_t ws_size,
                              hipStream_t stream) {
    const float* x   = (const float*)d_in[0];
    const float* hn  = (const float*)d_in[1];
    const float* Wih = (const float*)d_in[2];
    const float* Whh = (const float*)d_in[3];
    const float* bih = (const float*)d_in[4];
    const float* bhh = (const float*)d_in[5];
    const float* Wl  = (const float*)d_in[6];
    const float* bl  = (const float*)d_in[7];
    float* out = (float*)d_out;
    float* ws  = (float*)d_ws;   // 512*2*8*4 = 32 KB

    lstm_v18_kernel<<<dim3(512), dim3(256), 0, stream>>>(x, hn, Wih, Whh, bih, bhh, Wl, ws);
    reduce_kernel<<<dim3(4), dim3(256), 0, stream>>>(ws, bl, out);
}